// Round 4
// baseline (1110.641 us; speedup 1.0000x reference)
//
#include <hip/hip_runtime.h>
#include <math.h>

#define N_PER 25000
#define HID 256
#define E_PER 200000

typedef unsigned short ushort_t;
typedef __attribute__((ext_vector_type(8))) unsigned short ushort8v;
typedef __attribute__((ext_vector_type(4))) unsigned short ushort4v;
typedef __attribute__((ext_vector_type(8))) __bf16 bf16x8;
typedef __attribute__((ext_vector_type(4))) float floatx4;

__device__ __forceinline__ float bf2f(unsigned short u) {
    union { unsigned int i; float f; } c; c.i = ((unsigned int)u) << 16; return c.f;
}
__device__ __forceinline__ unsigned short f2bf(float f) {
    union { float f; unsigned int i; } c; c.f = f;
    unsigned int i = c.i;
    return (unsigned short)((i + 0x7FFFu + ((i >> 16) & 1u)) >> 16);
}

// ---------------- degree counting ----------------
__global__ void k_count(const int* __restrict__ es, const int* __restrict__ ed,
                        int* __restrict__ cnt_s, int* __restrict__ cnt_d) {
    int i = blockIdx.x * 256 + threadIdx.x;
    if (i >= 2 * E_PER) return;
    int et = i / E_PER;
    atomicAdd(&cnt_s[et * N_PER + es[i]], 1);
    atomicAdd(&cnt_d[et * N_PER + ed[i]], 1);
}

__global__ void k_scale(const int* __restrict__ cnt_s, const int* __restrict__ cnt_d,
                        float* __restrict__ cs, float* __restrict__ cd) {
    int i = blockIdx.x * 256 + threadIdx.x;
    if (i >= 2 * N_PER) return;
    cs[i] = rsqrtf(fmaxf((float)cnt_s[i], 1.f));
    cd[i] = rsqrtf(fmaxf((float)cnt_d[i], 1.f));
}

// ---------------- CSR build: scan + fill ----------------
__global__ __launch_bounds__(1024) void k_scan(const int* __restrict__ cnt,
                                               int* __restrict__ off, int* __restrict__ cur) {
    int et = blockIdx.x, t = threadIdx.x;
    const int* c = cnt + et * N_PER;
    int loc[25]; int tot = 0;
#pragma unroll
    for (int j = 0; j < 25; j++) {
        int idx = t * 25 + j;
        int v = (idx < N_PER) ? c[idx] : 0;
        loc[j] = tot; tot += v;
    }
    __shared__ int sb[1024];
    sb[t] = tot; __syncthreads();
    for (int d = 1; d < 1024; d <<= 1) {
        int v = (t >= d) ? sb[t - d] : 0;
        __syncthreads();
        sb[t] += v;
        __syncthreads();
    }
    int base = sb[t] - tot;
#pragma unroll
    for (int j = 0; j < 25; j++) {
        int idx = t * 25 + j;
        if (idx <= N_PER) {
            int val = base + loc[j];
            off[et * (N_PER + 1) + idx] = val;
            if (idx < N_PER) cur[et * N_PER + idx] = val;
        }
    }
}

__global__ void k_fill(const int* __restrict__ es, const int* __restrict__ ed,
                       int* __restrict__ cur, int* __restrict__ csr) {
    int i = blockIdx.x * 256 + threadIdx.x;
    if (i >= 2 * E_PER) return;
    int et = i / E_PER;
    int d = ed[i];
    int pos = atomicAdd(&cur[et * N_PER + d], 1);
    csr[et * E_PER + pos] = es[i];
}

// ---------------- weight convert (fp32 [K][N] -> bf16 [N][K]) ----------
// layout (elems): pre[2][256][256] @0, post @131072, qkv[2][768][256] @262144,
//                 o @655360, w1[2][512][256] @786432, w2[2][256][512] @1048576
__global__ void k_convw(const float* __restrict__ pre, const float* __restrict__ post,
                        const float* __restrict__ qW, const float* __restrict__ kW,
                        const float* __restrict__ vW, const float* __restrict__ oW,
                        const float* __restrict__ w1, const float* __restrict__ w2,
                        ushort_t* __restrict__ out) {
    int i = blockIdx.x * 256 + threadIdx.x;
    if (i >= 1310720) return;
    float v;
    if (i < 131072) {
        int z = i >> 16, n = (i >> 8) & 255, k = i & 255;
        v = pre[z * 65536 + k * 256 + n];
    } else if (i < 262144) {
        int j = i - 131072; int z = j >> 16, n = (j >> 8) & 255, k = j & 255;
        v = post[z * 65536 + k * 256 + n];
    } else if (i < 655360) {
        int j = i - 262144;
        int z = (j >= 196608) ? 1 : 0;
        int r = j - z * 196608;
        int row = r >> 8, k = r & 255;
        int mat = row >> 8, c = row & 255;
        const float* src = (mat == 0) ? qW : (mat == 1) ? kW : vW;
        v = src[z * 65536 + k * 256 + c];
    } else if (i < 786432) {
        int j = i - 655360; int z = j >> 16, n = (j >> 8) & 255, k = j & 255;
        v = oW[z * 65536 + k * 256 + n];
    } else if (i < 1048576) {
        int j = i - 786432; int z = j >> 17, r = j & 131071;
        int n = r >> 8, k = r & 255;
        v = w1[z * 131072 + k * 512 + n];
    } else {
        int j = i - 1048576; int z = j >> 17, r = j & 131071;
        int n = r >> 9, k = r & 511;
        v = w2[z * 131072 + k * 256 + n];
    }
    out[i] = f2bf(v);
}

// pack q/k/v biases -> [2][768]
__global__ void k_packbias(const float* __restrict__ qb, const float* __restrict__ kb,
                           const float* __restrict__ vb, float* __restrict__ out) {
    int i = blockIdx.x * 256 + threadIdx.x;
    if (i >= 1536) return;
    int z = i / 768, c = i % 768;
    int mat = c >> 8, cc = c & 255;
    const float* src = (mat == 0) ? qb : (mat == 1) ? kb : vb;
    out[i] = src[z * 256 + cc];
}

// ---------------- LayerNorm (+optional cs scale) -> bf16 ----------------
__global__ __launch_bounds__(256) void k_ln(const float* __restrict__ h,
                                            const float* __restrict__ g, const float* __restrict__ b,
                                            const float* __restrict__ cs, ushort_t* __restrict__ out) {
    int lane = threadIdx.x & 63;
    int row = blockIdx.x * 4 + (threadIdx.x >> 6);
    int ty = row >= N_PER;
    float4 x = *(const float4*)(h + (size_t)row * HID + lane * 4);
    float s = x.x + x.y + x.z + x.w;
    float q = x.x * x.x + x.y * x.y + x.z * x.z + x.w * x.w;
    for (int m = 1; m < 64; m <<= 1) {
        s += __shfl_xor(s, m, 64);
        q += __shfl_xor(q, m, 64);
    }
    float mean = s * (1.f / 256.f);
    float var = q * (1.f / 256.f) - mean * mean;
    float rs = rsqrtf(var + 1e-5f);
    float sc = cs ? cs[row] : 1.f;
    int c = lane * 4;
    const float* gp = g + ty * HID + c;
    const float* bp = b + ty * HID + c;
    float xv[4] = {x.x, x.y, x.z, x.w};
    ushort4v o;
#pragma unroll
    for (int i = 0; i < 4; i++) {
        float y = ((xv[i] - mean) * rs * gp[i] + bp[i]) * sc;
        o[i] = f2bf(y);
    }
    *(ushort4v*)(out + (size_t)row * HID + c) = o;
}

// ---------------- conv gather (4-wide unrolled) ----------------
__global__ __launch_bounds__(256) void k_gather(const ushort_t* __restrict__ hn,
                                                const int* __restrict__ off, const int* __restrict__ csr,
                                                ushort_t* __restrict__ agg) {
    int lane = threadIdx.x & 63;
    int row = blockIdx.x * 4 + (threadIdx.x >> 6);
    int dt = row >= N_PER;
    int n = row - dt * N_PER;
    int et = 1 - dt;
    int s0 = off[et * (N_PER + 1) + n], s1 = off[et * (N_PER + 1) + n + 1];
    const ushort_t* hb = hn + (size_t)et * N_PER * HID + lane * 4;
    const int* list = csr + et * E_PER;
    float a0 = 0, a1 = 0, a2 = 0, a3 = 0;
    int e = s0;
    for (; e + 4 <= s1; e += 4) {
        int ia = list[e], ib = list[e + 1], ic = list[e + 2], id = list[e + 3];
        ushort4v ua = *(const ushort4v*)(hb + (size_t)ia * HID);
        ushort4v ub = *(const ushort4v*)(hb + (size_t)ib * HID);
        ushort4v uc = *(const ushort4v*)(hb + (size_t)ic * HID);
        ushort4v ud = *(const ushort4v*)(hb + (size_t)id * HID);
        a0 += bf2f(ua[0]) + bf2f(ub[0]) + bf2f(uc[0]) + bf2f(ud[0]);
        a1 += bf2f(ua[1]) + bf2f(ub[1]) + bf2f(uc[1]) + bf2f(ud[1]);
        a2 += bf2f(ua[2]) + bf2f(ub[2]) + bf2f(uc[2]) + bf2f(ud[2]);
        a3 += bf2f(ua[3]) + bf2f(ub[3]) + bf2f(uc[3]) + bf2f(ud[3]);
    }
    for (; e < s1; ++e) {
        int src = list[e];
        ushort4v u = *(const ushort4v*)(hb + (size_t)src * HID);
        a0 += bf2f(u[0]); a1 += bf2f(u[1]); a2 += bf2f(u[2]); a3 += bf2f(u[3]);
    }
    ushort4v o; o[0] = f2bf(a0); o[1] = f2bf(a1); o[2] = f2bf(a2); o[3] = f2bf(a3);
    *(ushort4v*)(agg + ((size_t)et * N_PER + n) * HID + lane * 4) = o;
}

// ---------------- fused edge softmax attention (2-wide unrolled) ----------------
__global__ __launch_bounds__(256) void k_attn(const ushort_t* __restrict__ q,
                                              const ushort_t* __restrict__ k, const ushort_t* __restrict__ v,
                                              const int* __restrict__ off, const int* __restrict__ csr,
                                              ushort_t* __restrict__ outb) {
    int lane = threadIdx.x & 63;
    int row = blockIdx.x * 4 + (threadIdx.x >> 6);
    int dt = row >= N_PER;
    int n = row - dt * N_PER;
    int et = 1 - dt;
    int s0 = off[et * (N_PER + 1) + n], s1 = off[et * (N_PER + 1) + n + 1];
    ushort4v qu = *(const ushort4v*)(q + (size_t)row * HID + lane * 4);
    float q0 = bf2f(qu[0]), q1 = bf2f(qu[1]), q2 = bf2f(qu[2]), q3 = bf2f(qu[3]);
    const ushort_t* kb = k + (size_t)et * N_PER * HID + lane * 4;
    const ushort_t* vb = v + (size_t)et * N_PER * HID + lane * 4;
    const int* list = csr + et * E_PER;
    float l = 0.f;
    float O0 = 0, O1 = 0, O2 = 0, O3 = 0;
    int e = s0;
    for (; e + 2 <= s1; e += 2) {
        int ia = list[e], ib = list[e + 1];
        ushort4v kua = *(const ushort4v*)(kb + (size_t)ia * HID);
        ushort4v vua = *(const ushort4v*)(vb + (size_t)ia * HID);
        ushort4v kub = *(const ushort4v*)(kb + (size_t)ib * HID);
        ushort4v vub = *(const ushort4v*)(vb + (size_t)ib * HID);
        float da = q0 * bf2f(kua[0]) + q1 * bf2f(kua[1]) + q2 * bf2f(kua[2]) + q3 * bf2f(kua[3]);
        float db = q0 * bf2f(kub[0]) + q1 * bf2f(kub[1]) + q2 * bf2f(kub[2]) + q3 * bf2f(kub[3]);
        da += __shfl_xor(da, 1, 64); db += __shfl_xor(db, 1, 64);
        da += __shfl_xor(da, 2, 64); db += __shfl_xor(db, 2, 64);
        da += __shfl_xor(da, 4, 64); db += __shfl_xor(db, 4, 64);
        float sa = fminf(5.f, fmaxf(-5.f, da * 0.17677669529663687f));
        float sb = fminf(5.f, fmaxf(-5.f, db * 0.17677669529663687f));
        float pa = __expf(sa), pb = __expf(sb);
        l += pa + pb;
        O0 += pa * bf2f(vua[0]) + pb * bf2f(vub[0]);
        O1 += pa * bf2f(vua[1]) + pb * bf2f(vub[1]);
        O2 += pa * bf2f(vua[2]) + pb * bf2f(vub[2]);
        O3 += pa * bf2f(vua[3]) + pb * bf2f(vub[3]);
    }
    if (e < s1) {
        int src = list[e];
        ushort4v ku = *(const ushort4v*)(kb + (size_t)src * HID);
        ushort4v vu = *(const ushort4v*)(vb + (size_t)src * HID);
        float d = q0 * bf2f(ku[0]) + q1 * bf2f(ku[1]) + q2 * bf2f(ku[2]) + q3 * bf2f(ku[3]);
        d += __shfl_xor(d, 1, 64);
        d += __shfl_xor(d, 2, 64);
        d += __shfl_xor(d, 4, 64);
        float s = fminf(5.f, fmaxf(-5.f, d * 0.17677669529663687f));
        float p = __expf(s);
        l += p;
        O0 += p * bf2f(vu[0]); O1 += p * bf2f(vu[1]);
        O2 += p * bf2f(vu[2]); O3 += p * bf2f(vu[3]);
    }
    float inv = (l > 0.f) ? 1.f / l : 0.f;
    ushort4v o;
    o[0] = f2bf(O0 * inv); o[1] = f2bf(O1 * inv); o[2] = f2bf(O2 * inv); o[3] = f2bf(O3 * inv);
    *(ushort4v*)(outb + (size_t)row * HID + lane * 4) = o;
}

// ---------------- LDS-free per-wave MFMA GEMM ----------------
// 256 threads = 4 independent waves; each wave: 16 rows x all N cols.
// A-frags hoisted to VGPRs once; B-frags loaded global->VGPR (L1/L2-resident
// weights, 64B-line coalesced). No LDS, no barriers. 4 concurrent MFMA chains.
// MODE 0: fout[zo][m][col] = base[zo][m][col] + acc*sc + bias  (conv/o/ffn2)
// MODE 1: qkv bf16 split by col>>8
// MODE 2: ffn1 bf16 gelu, row stride 512
template <int MODE, int KT, int NCB, int MINW>
__global__ __launch_bounds__(256, MINW)
void k_gemm4(const ushort_t* __restrict__ A, long Az,
             const ushort_t* __restrict__ BT, long Bz,
             const float* __restrict__ bias,
             const float* __restrict__ base, float* __restrict__ fout, int swapz,
             ushort_t* __restrict__ bout, const float* __restrict__ scale) {
    constexpr int K = KT * 32;
    constexpr int BCOLS = NCB * 16;
    const int t = threadIdx.x;
    const int lane = t & 63, w = t >> 6;
    const int ml = lane & 15, qo = lane >> 4;
    const int z = blockIdx.z;
    const int arow = blockIdx.x * 64 + w * 16 + ml;     // row this lane's A-frag covers
    const ushort_t* Ab = A + (long)z * Az;
    const ushort_t* Bb = BT + (long)z * Bz;
    const ushort8v z8 = {0, 0, 0, 0, 0, 0, 0, 0};

    // hoist A fragments (read A exactly once per GEMM)
    ushort8v afr[KT];
#pragma unroll
    for (int kt = 0; kt < KT; kt++)
        afr[kt] = (arow < N_PER) ? *(const ushort8v*)(Ab + (long)arow * K + kt * 32 + qo * 8) : z8;

    const int mbase = blockIdx.x * 64 + w * 16 + qo * 4;   // C rows this lane owns
    float sc[4];
#pragma unroll
    for (int r = 0; r < 4; r++)
        sc[r] = (MODE == 0 && scale && mbase + r < N_PER) ? scale[z * N_PER + mbase + r] : 1.f;
    const int zo = (MODE == 0 && swapz) ? 1 - z : z;

    for (int j0 = 0; j0 < NCB; j0 += 4) {
        floatx4 acc[4];
#pragma unroll
        for (int u = 0; u < 4; u++) acc[u] = (floatx4){0.f, 0.f, 0.f, 0.f};
#pragma unroll
        for (int kt = 0; kt < KT; kt++) {
#pragma unroll
            for (int u = 0; u < 4; u++) {
                bf16x8 bfr = *(const bf16x8*)(Bb + (long)((j0 + u) * 16 + ml) * K + kt * 32 + qo * 8);
                acc[u] = __builtin_amdgcn_mfma_f32_16x16x32_bf16(*(bf16x8*)&afr[kt], bfr, acc[u], 0, 0, 0);
            }
        }
#pragma unroll
        for (int u = 0; u < 4; u++) {
            int col = (j0 + u) * 16 + ml;
            float bv = bias[z * BCOLS + col];
#pragma unroll
            for (int r = 0; r < 4; r++) {
                int m = mbase + r;
                if (m >= N_PER) continue;
                float vv = acc[u][r];
                if (MODE == 0) {
                    vv = vv * sc[r] + bv;
                    size_t idx = ((size_t)zo * N_PER + m) * 256 + col;
                    fout[idx] = base[idx] + vv;
                } else if (MODE == 1) {
                    vv += bv;
                    int mat = col >> 8, cc = col & 255;
                    bout[((size_t)mat * 2 * N_PER + (size_t)z * N_PER + m) * 256 + cc] = f2bf(vv);
                } else {
                    vv += bv;
                    vv = 0.5f * vv * (1.0f + erff(vv * 0.70710678118654752f));
                    bout[((size_t)z * N_PER + m) * 512 + col] = f2bf(vv);
                }
            }
        }
    }
}

extern "C" void kernel_launch(void* const* d_in, const int* in_sizes, int n_in,
                              void* d_out, int out_size, void* d_ws, size_t ws_size,
                              hipStream_t stream) {
    const float* h_in   = (const float*)d_in[0];
    const int*   e_src  = (const int*)d_in[1];
    const int*   e_dst  = (const int*)d_in[2];
    const float* pre_W  = (const float*)d_in[3];
    const float* pre_b  = (const float*)d_in[4];
    const float* post_W = (const float*)d_in[5];
    const float* post_b = (const float*)d_in[6];
    const float* q_W    = (const float*)d_in[7];
    const float* q_b    = (const float*)d_in[8];
    const float* k_W    = (const float*)d_in[9];
    const float* k_b    = (const float*)d_in[10];
    const float* v_W    = (const float*)d_in[11];
    const float* v_b    = (const float*)d_in[12];
    const float* o_W    = (const float*)d_in[13];
    const float* o_b    = (const float*)d_in[14];
    const float* ffn_W1 = (const float*)d_in[15];
    const float* ffn_b1 = (const float*)d_in[16];
    const float* ffn_W2 = (const float*)d_in[17];
    const float* ffn_b2 = (const float*)d_in[18];
    const float* ln_pre_g  = (const float*)d_in[19];
    const float* ln_pre_b  = (const float*)d_in[20];
    const float* ln_attn_g = (const float*)d_in[21];
    const float* ln_attn_b = (const float*)d_in[22];
    const float* ln_post_g = (const float*)d_in[23];
    const float* ln_post_b = (const float*)d_in[24];
    const float* ln_ffn_g  = (const float*)d_in[25];
    const float* ln_ffn_b  = (const float*)d_in[26];

    float* hout = (float*)d_out;
    char* ws = (char*)d_ws;

    const long AzH = (long)N_PER * HID;                 // 6.4M elems

    // workspace layout (bytes)
    ushort_t* hn    = (ushort_t*)(ws + 0);              // 25.6 MB bf16 [2][25000][256]
    ushort_t* qkv   = (ushort_t*)(ws + 25600000);       // 76.8 MB bf16 [3][2][25000][256]
    ushort_t* fb    = (ushort_t*)(ws + 25600000);       // 51.2 MB bf16 [2][25000][512] (aliases q+k)
    ushort_t* agg   = (ushort_t*)(ws + 102400000);      // 25.6 MB
    ushort_t* wT    = (ushort_t*)(ws + 128000000);      // 2.62 MB
    float* qkvbias  = (float*)(ws + 130621440);         // 6 KB
    float* cs       = (float*)(ws + 130627584);
    float* cd       = (float*)(ws + 130827584);
    int* cnt_s      = (int*)(ws + 131027584);
    int* cnt_d      = (int*)(ws + 131227584);
    int* off        = (int*)(ws + 131427584);
    int* cur        = (int*)(ws + 131627592);
    int* csr        = (int*)(ws + 131827592);

    const ushort_t* preWT  = wT;
    const ushort_t* postWT = wT + 131072;
    const ushort_t* qkvWT  = wT + 262144;
    const ushort_t* oWT    = wT + 655360;
    const ushort_t* w1T    = wT + 786432;
    const ushort_t* w2T    = wT + 1048576;
    ushort_t* qb = qkv;                                  // [2][N][256]
    ushort_t* kb = qkv + 2 * AzH;
    ushort_t* vb = qkv + 4 * AzH;

    hipMemsetAsync(cnt_s, 0, 400000, stream);            // cnt_s + cnt_d contiguous

    k_convw<<<5120, 256, 0, stream>>>(pre_W, post_W, q_W, k_W, v_W, o_W, ffn_W1, ffn_W2, wT);
    k_packbias<<<6, 256, 0, stream>>>(q_b, k_b, v_b, qkvbias);
    k_count<<<1563, 256, 0, stream>>>(e_src, e_dst, cnt_s, cnt_d);
    k_scale<<<196, 256, 0, stream>>>(cnt_s, cnt_d, cs, cd);
    k_scan<<<2, 1024, 0, stream>>>(cnt_d, off, cur);
    k_fill<<<1563, 256, 0, stream>>>(e_src, e_dst, cur, csr);

    // ---- stage 1: pre hetero-conv ----
    k_ln<<<12500, 256, 0, stream>>>(h_in, ln_pre_g, ln_pre_b, cs, hn);
    k_gather<<<12500, 256, 0, stream>>>(hn, off, csr, agg);
    k_gemm4<0, 8, 16, 4><<<dim3(391, 1, 2), 256, 0, stream>>>(agg, AzH, preWT, 65536, pre_b,
                                                              h_in, hout, 1, (ushort_t*)nullptr, cd);

    // ---- stage 2: sparse attention ----
    k_ln<<<12500, 256, 0, stream>>>(hout, ln_attn_g, ln_attn_b, (const float*)nullptr, hn);
    k_gemm4<1, 8, 48, 4><<<dim3(391, 1, 2), 256, 0, stream>>>(hn, AzH, qkvWT, 196608, qkvbias,
                                                              (const float*)nullptr, (float*)nullptr, 0,
                                                              qkv, (const float*)nullptr);
    k_attn<<<12500, 256, 0, stream>>>(qb, kb, vb, off, csr, agg);
    k_gemm4<0, 8, 16, 4><<<dim3(391, 1, 2), 256, 0, stream>>>(agg, AzH, oWT, 65536, o_b,
                                                              hout, hout, 0, (ushort_t*)nullptr,
                                                              (const float*)nullptr);

    // ---- stage 3: post hetero-conv ----
    k_ln<<<12500, 256, 0, stream>>>(hout, ln_post_g, ln_post_b, cs, hn);
    k_gather<<<12500, 256, 0, stream>>>(hn, off, csr, agg);
    k_gemm4<0, 8, 16, 4><<<dim3(391, 1, 2), 256, 0, stream>>>(agg, AzH, postWT, 65536, post_b,
                                                              hout, hout, 1, (ushort_t*)nullptr, cd);

    // ---- stage 4: FFN ----
    k_ln<<<12500, 256, 0, stream>>>(hout, ln_ffn_g, ln_ffn_b, (const float*)nullptr, hn);
    k_gemm4<2, 8, 32, 4><<<dim3(391, 1, 2), 256, 0, stream>>>(hn, AzH, w1T, 131072, ffn_b1,
                                                              (const float*)nullptr, (float*)nullptr, 0,
                                                              fb, (const float*)nullptr);
    k_gemm4<0, 16, 16, 3><<<dim3(391, 1, 2), 256, 0, stream>>>(fb, (long)N_PER * 512, w2T, 131072, ffn_b2,
                                                               hout, hout, 0, (ushort_t*)nullptr,
                                                               (const float*)nullptr);
}

// Round 5
// 759.748 us; speedup vs baseline: 1.4619x; 1.4619x over previous
//
#include <hip/hip_runtime.h>
#include <math.h>

#define N_PER 25000
#define HID 256
#define E_PER 200000

typedef unsigned short ushort_t;
typedef __attribute__((ext_vector_type(8))) unsigned short ushort8v;
typedef __attribute__((ext_vector_type(4))) unsigned short ushort4v;
typedef __attribute__((ext_vector_type(8))) __bf16 bf16x8;
typedef __attribute__((ext_vector_type(4))) float floatx4;

__device__ __forceinline__ float bf2f(unsigned short u) {
    union { unsigned int i; float f; } c; c.i = ((unsigned int)u) << 16; return c.f;
}
__device__ __forceinline__ unsigned short f2bf(float f) {
    union { float f; unsigned int i; } c; c.f = f;
    unsigned int i = c.i;
    return (unsigned short)((i + 0x7FFFu + ((i >> 16) & 1u)) >> 16);
}

// ---------------- degree counting ----------------
__global__ void k_count(const int* __restrict__ es, const int* __restrict__ ed,
                        int* __restrict__ cnt_s, int* __restrict__ cnt_d) {
    int i = blockIdx.x * 256 + threadIdx.x;
    if (i >= 2 * E_PER) return;
    int et = i / E_PER;
    atomicAdd(&cnt_s[et * N_PER + es[i]], 1);
    atomicAdd(&cnt_d[et * N_PER + ed[i]], 1);
}

__global__ void k_scale(const int* __restrict__ cnt_s, const int* __restrict__ cnt_d,
                        float* __restrict__ cs, float* __restrict__ cd) {
    int i = blockIdx.x * 256 + threadIdx.x;
    if (i >= 2 * N_PER) return;
    cs[i] = rsqrtf(fmaxf((float)cnt_s[i], 1.f));
    cd[i] = rsqrtf(fmaxf((float)cnt_d[i], 1.f));
}

// ---------------- CSR build: scan + fill ----------------
__global__ __launch_bounds__(1024) void k_scan(const int* __restrict__ cnt,
                                               int* __restrict__ off, int* __restrict__ cur) {
    int et = blockIdx.x, t = threadIdx.x;
    const int* c = cnt + et * N_PER;
    int loc[25]; int tot = 0;
#pragma unroll
    for (int j = 0; j < 25; j++) {
        int idx = t * 25 + j;
        int v = (idx < N_PER) ? c[idx] : 0;
        loc[j] = tot; tot += v;
    }
    __shared__ int sb[1024];
    sb[t] = tot; __syncthreads();
    for (int d = 1; d < 1024; d <<= 1) {
        int v = (t >= d) ? sb[t - d] : 0;
        __syncthreads();
        sb[t] += v;
        __syncthreads();
    }
    int base = sb[t] - tot;
#pragma unroll
    for (int j = 0; j < 25; j++) {
        int idx = t * 25 + j;
        if (idx <= N_PER) {
            int val = base + loc[j];
            off[et * (N_PER + 1) + idx] = val;
            if (idx < N_PER) cur[et * N_PER + idx] = val;
        }
    }
}

__global__ void k_fill(const int* __restrict__ es, const int* __restrict__ ed,
                       int* __restrict__ cur, int* __restrict__ csr) {
    int i = blockIdx.x * 256 + threadIdx.x;
    if (i >= 2 * E_PER) return;
    int et = i / E_PER;
    int d = ed[i];
    int pos = atomicAdd(&cur[et * N_PER + d], 1);
    csr[et * E_PER + pos] = es[i];
}

// ---------------- weight convert (fp32 [K][N] -> bf16 [N][K]) ----------
// layout (elems): pre[2][256][256] @0, post @131072, qkv[2][768][256] @262144,
//                 o @655360, w1[2][512][256] @786432, w2[2][256][512] @1048576
__global__ void k_convw(const float* __restrict__ pre, const float* __restrict__ post,
                        const float* __restrict__ qW, const float* __restrict__ kW,
                        const float* __restrict__ vW, const float* __restrict__ oW,
                        const float* __restrict__ w1, const float* __restrict__ w2,
                        ushort_t* __restrict__ out) {
    int i = blockIdx.x * 256 + threadIdx.x;
    if (i >= 1310720) return;
    float v;
    if (i < 131072) {
        int z = i >> 16, n = (i >> 8) & 255, k = i & 255;
        v = pre[z * 65536 + k * 256 + n];
    } else if (i < 262144) {
        int j = i - 131072; int z = j >> 16, n = (j >> 8) & 255, k = j & 255;
        v = post[z * 65536 + k * 256 + n];
    } else if (i < 655360) {
        int j = i - 262144;
        int z = (j >= 196608) ? 1 : 0;
        int r = j - z * 196608;
        int row = r >> 8, k = r & 255;
        int mat = row >> 8, c = row & 255;
        const float* src = (mat == 0) ? qW : (mat == 1) ? kW : vW;
        v = src[z * 65536 + k * 256 + c];
    } else if (i < 786432) {
        int j = i - 655360; int z = j >> 16, n = (j >> 8) & 255, k = j & 255;
        v = oW[z * 65536 + k * 256 + n];
    } else if (i < 1048576) {
        int j = i - 786432; int z = j >> 17, r = j & 131071;
        int n = r >> 8, k = r & 255;
        v = w1[z * 131072 + k * 512 + n];
    } else {
        int j = i - 1048576; int z = j >> 17, r = j & 131071;
        int n = r >> 9, k = r & 511;
        v = w2[z * 131072 + k * 256 + n];
    }
    out[i] = f2bf(v);
}

// pack q/k/v biases -> [2][768]
__global__ void k_packbias(const float* __restrict__ qb, const float* __restrict__ kb,
                           const float* __restrict__ vb, float* __restrict__ out) {
    int i = blockIdx.x * 256 + threadIdx.x;
    if (i >= 1536) return;
    int z = i / 768, c = i % 768;
    int mat = c >> 8, cc = c & 255;
    const float* src = (mat == 0) ? qb : (mat == 1) ? kb : vb;
    out[i] = src[z * 256 + cc];
}

// ---------------- LayerNorm (+optional cs scale) -> bf16 ----------------
__global__ __launch_bounds__(256) void k_ln(const float* __restrict__ h,
                                            const float* __restrict__ g, const float* __restrict__ b,
                                            const float* __restrict__ cs, ushort_t* __restrict__ out) {
    int lane = threadIdx.x & 63;
    int row = blockIdx.x * 4 + (threadIdx.x >> 6);
    int ty = row >= N_PER;
    float4 x = *(const float4*)(h + (size_t)row * HID + lane * 4);
    float s = x.x + x.y + x.z + x.w;
    float q = x.x * x.x + x.y * x.y + x.z * x.z + x.w * x.w;
    for (int m = 1; m < 64; m <<= 1) {
        s += __shfl_xor(s, m, 64);
        q += __shfl_xor(q, m, 64);
    }
    float mean = s * (1.f / 256.f);
    float var = q * (1.f / 256.f) - mean * mean;
    float rs = rsqrtf(var + 1e-5f);
    float sc = cs ? cs[row] : 1.f;
    int c = lane * 4;
    const float* gp = g + ty * HID + c;
    const float* bp = b + ty * HID + c;
    float xv[4] = {x.x, x.y, x.z, x.w};
    ushort4v o;
#pragma unroll
    for (int i = 0; i < 4; i++) {
        float y = ((xv[i] - mean) * rs * gp[i] + bp[i]) * sc;
        o[i] = f2bf(y);
    }
    *(ushort4v*)(out + (size_t)row * HID + c) = o;
}

// ---------------- conv gather (4-wide unrolled) ----------------
__global__ __launch_bounds__(256) void k_gather(const ushort_t* __restrict__ hn,
                                                const int* __restrict__ off, const int* __restrict__ csr,
                                                ushort_t* __restrict__ agg) {
    int lane = threadIdx.x & 63;
    int row = blockIdx.x * 4 + (threadIdx.x >> 6);
    int dt = row >= N_PER;
    int n = row - dt * N_PER;
    int et = 1 - dt;
    int s0 = off[et * (N_PER + 1) + n], s1 = off[et * (N_PER + 1) + n + 1];
    const ushort_t* hb = hn + (size_t)et * N_PER * HID + lane * 4;
    const int* list = csr + et * E_PER;
    float a0 = 0, a1 = 0, a2 = 0, a3 = 0;
    int e = s0;
    for (; e + 4 <= s1; e += 4) {
        int ia = list[e], ib = list[e + 1], ic = list[e + 2], id = list[e + 3];
        ushort4v ua = *(const ushort4v*)(hb + (size_t)ia * HID);
        ushort4v ub = *(const ushort4v*)(hb + (size_t)ib * HID);
        ushort4v uc = *(const ushort4v*)(hb + (size_t)ic * HID);
        ushort4v ud = *(const ushort4v*)(hb + (size_t)id * HID);
        a0 += bf2f(ua[0]) + bf2f(ub[0]) + bf2f(uc[0]) + bf2f(ud[0]);
        a1 += bf2f(ua[1]) + bf2f(ub[1]) + bf2f(uc[1]) + bf2f(ud[1]);
        a2 += bf2f(ua[2]) + bf2f(ub[2]) + bf2f(uc[2]) + bf2f(ud[2]);
        a3 += bf2f(ua[3]) + bf2f(ub[3]) + bf2f(uc[3]) + bf2f(ud[3]);
    }
    for (; e < s1; ++e) {
        int src = list[e];
        ushort4v u = *(const ushort4v*)(hb + (size_t)src * HID);
        a0 += bf2f(u[0]); a1 += bf2f(u[1]); a2 += bf2f(u[2]); a3 += bf2f(u[3]);
    }
    ushort4v o; o[0] = f2bf(a0); o[1] = f2bf(a1); o[2] = f2bf(a2); o[3] = f2bf(a3);
    *(ushort4v*)(agg + ((size_t)et * N_PER + n) * HID + lane * 4) = o;
}

// ---------------- fused edge softmax attention (2-wide unrolled) ----------------
__global__ __launch_bounds__(256) void k_attn(const ushort_t* __restrict__ q,
                                              const ushort_t* __restrict__ k, const ushort_t* __restrict__ v,
                                              const int* __restrict__ off, const int* __restrict__ csr,
                                              ushort_t* __restrict__ outb) {
    int lane = threadIdx.x & 63;
    int row = blockIdx.x * 4 + (threadIdx.x >> 6);
    int dt = row >= N_PER;
    int n = row - dt * N_PER;
    int et = 1 - dt;
    int s0 = off[et * (N_PER + 1) + n], s1 = off[et * (N_PER + 1) + n + 1];
    ushort4v qu = *(const ushort4v*)(q + (size_t)row * HID + lane * 4);
    float q0 = bf2f(qu[0]), q1 = bf2f(qu[1]), q2 = bf2f(qu[2]), q3 = bf2f(qu[3]);
    const ushort_t* kb = k + (size_t)et * N_PER * HID + lane * 4;
    const ushort_t* vb = v + (size_t)et * N_PER * HID + lane * 4;
    const int* list = csr + et * E_PER;
    float l = 0.f;
    float O0 = 0, O1 = 0, O2 = 0, O3 = 0;
    int e = s0;
    for (; e + 2 <= s1; e += 2) {
        int ia = list[e], ib = list[e + 1];
        ushort4v kua = *(const ushort4v*)(kb + (size_t)ia * HID);
        ushort4v vua = *(const ushort4v*)(vb + (size_t)ia * HID);
        ushort4v kub = *(const ushort4v*)(kb + (size_t)ib * HID);
        ushort4v vub = *(const ushort4v*)(vb + (size_t)ib * HID);
        float da = q0 * bf2f(kua[0]) + q1 * bf2f(kua[1]) + q2 * bf2f(kua[2]) + q3 * bf2f(kua[3]);
        float db = q0 * bf2f(kub[0]) + q1 * bf2f(kub[1]) + q2 * bf2f(kub[2]) + q3 * bf2f(kub[3]);
        da += __shfl_xor(da, 1, 64); db += __shfl_xor(db, 1, 64);
        da += __shfl_xor(da, 2, 64); db += __shfl_xor(db, 2, 64);
        da += __shfl_xor(da, 4, 64); db += __shfl_xor(db, 4, 64);
        float sa = fminf(5.f, fmaxf(-5.f, da * 0.17677669529663687f));
        float sb = fminf(5.f, fmaxf(-5.f, db * 0.17677669529663687f));
        float pa = __expf(sa), pb = __expf(sb);
        l += pa + pb;
        O0 += pa * bf2f(vua[0]) + pb * bf2f(vub[0]);
        O1 += pa * bf2f(vua[1]) + pb * bf2f(vub[1]);
        O2 += pa * bf2f(vua[2]) + pb * bf2f(vub[2]);
        O3 += pa * bf2f(vua[3]) + pb * bf2f(vub[3]);
    }
    if (e < s1) {
        int src = list[e];
        ushort4v ku = *(const ushort4v*)(kb + (size_t)src * HID);
        ushort4v vu = *(const ushort4v*)(vb + (size_t)src * HID);
        float d = q0 * bf2f(ku[0]) + q1 * bf2f(ku[1]) + q2 * bf2f(ku[2]) + q3 * bf2f(ku[3]);
        d += __shfl_xor(d, 1, 64);
        d += __shfl_xor(d, 2, 64);
        d += __shfl_xor(d, 4, 64);
        float s = fminf(5.f, fmaxf(-5.f, d * 0.17677669529663687f));
        float p = __expf(s);
        l += p;
        O0 += p * bf2f(vu[0]); O1 += p * bf2f(vu[1]);
        O2 += p * bf2f(vu[2]); O3 += p * bf2f(vu[3]);
    }
    float inv = (l > 0.f) ? 1.f / l : 0.f;
    ushort4v o;
    o[0] = f2bf(O0 * inv); o[1] = f2bf(O1 * inv); o[2] = f2bf(O2 * inv); o[3] = f2bf(O3 * inv);
    *(ushort4v*)(outb + (size_t)row * HID + lane * 4) = o;
}

// ---------------- m97-style 128x128xBK32 double-buffered MFMA GEMM ----------------
// 256 thr = 2x2 waves, each wave 64x64 (4x4 MFMA 16x16x32 per k-iter).
// As/Bs 128x32 bf16, XOR-16B-chunk swizzle (zero bank conflicts, r3-verified),
// double-buffered: one barrier per k-iter, next-tile global loads overlap MFMAs.
// MODE 0: fout[zo][m][col] = base[zo][m][col] + acc*sc + bias  (conv/o/ffn2)
// MODE 1: qkv bf16 split by col>>8
// MODE 2: ffn1 bf16 gelu, row stride 512
template <int MODE, int KT>
__global__ __launch_bounds__(256, 3)
void k_gemm5(const ushort_t* __restrict__ A, long Az,
             const ushort_t* __restrict__ BT, long Bz,
             const float* __restrict__ bias,
             const float* __restrict__ base, float* __restrict__ fout, int swapz,
             ushort_t* __restrict__ bout, const float* __restrict__ scale) {
    constexpr int K = KT * 32;
    constexpr int BCOLS = (MODE == 1) ? 768 : (MODE == 2) ? 512 : 256;
    __shared__ __align__(16) ushort_t As[2][128 * 32];
    __shared__ __align__(16) ushort_t Bs[2][128 * 32];
    const int t = threadIdx.x;
    const int lane = t & 63, w = t >> 6;
    const int wm = w & 1, wn = w >> 1;
    const int ml = lane & 15, qo = lane >> 4;
    const int z = blockIdx.z;
    const int m0 = blockIdx.x * 128, n0 = blockIdx.y * 128;
    const ushort_t* Ab = A + (long)z * Az;
    const ushort_t* Bb = BT + (long)z * Bz;
    const ushort8v z8 = {0, 0, 0, 0, 0, 0, 0, 0};

    // staging: thread t owns row t>>1 (0..127), 16B chunks sc0,sc0+1 of the 4
    const int srow = t >> 1;
    const int sc0 = (t & 1) * 2;
    const int garow = m0 + srow;
    const long aGb = (long)garow * K + sc0 * 8;
    const long bGb = (long)(n0 + srow) * K + sc0 * 8;
    const int sw0 = srow * 32 + ((sc0 ^ (srow & 3)) << 3);
    const int sw1 = srow * 32 + (((sc0 + 1) ^ (srow & 3)) << 3);
    const bool aok = garow < N_PER;

    // fragment read offsets (swizzled): row i*16+ml, chunk qo
    int aro[4], bro[4];
#pragma unroll
    for (int i = 0; i < 4; i++) {
        aro[i] = (wm * 64 + i * 16 + ml) * 32 + ((qo ^ (ml & 3)) << 3);
        bro[i] = (wn * 64 + i * 16 + ml) * 32 + ((qo ^ (ml & 3)) << 3);
    }

    floatx4 acc[4][4];
#pragma unroll
    for (int i = 0; i < 4; i++)
#pragma unroll
        for (int j = 0; j < 4; j++) acc[i][j] = (floatx4){0.f, 0.f, 0.f, 0.f};

    // prologue: stage k-tile 0 into buffer 0
    {
        ushort8v a0 = aok ? *(const ushort8v*)(Ab + aGb) : z8;
        ushort8v a1 = aok ? *(const ushort8v*)(Ab + aGb + 8) : z8;
        ushort8v b0 = *(const ushort8v*)(Bb + bGb);
        ushort8v b1 = *(const ushort8v*)(Bb + bGb + 8);
        *(ushort8v*)(As[0] + sw0) = a0;
        *(ushort8v*)(As[0] + sw1) = a1;
        *(ushort8v*)(Bs[0] + sw0) = b0;
        *(ushort8v*)(Bs[0] + sw1) = b1;
    }

#pragma unroll
    for (int kt = 0; kt < KT; kt++) {
        __syncthreads();
        const int cur = kt & 1;
        bf16x8 af[4], bf[4];
#pragma unroll
        for (int i = 0; i < 4; i++) {
            af[i] = *(const bf16x8*)(As[cur] + aro[i]);
            bf[i] = *(const bf16x8*)(Bs[cur] + bro[i]);
        }
        if (kt + 1 < KT) {
            const int nk = (kt + 1) * 32;
            ushort8v a0 = aok ? *(const ushort8v*)(Ab + aGb + nk) : z8;
            ushort8v a1 = aok ? *(const ushort8v*)(Ab + aGb + nk + 8) : z8;
            ushort8v b0 = *(const ushort8v*)(Bb + bGb + nk);
            ushort8v b1 = *(const ushort8v*)(Bb + bGb + nk + 8);
            const int nb = cur ^ 1;
            *(ushort8v*)(As[nb] + sw0) = a0;
            *(ushort8v*)(As[nb] + sw1) = a1;
            *(ushort8v*)(Bs[nb] + sw0) = b0;
            *(ushort8v*)(Bs[nb] + sw1) = b1;
        }
#pragma unroll
        for (int i = 0; i < 4; i++)
#pragma unroll
            for (int j = 0; j < 4; j++)
                acc[i][j] = __builtin_amdgcn_mfma_f32_16x16x32_bf16(af[i], bf[j], acc[i][j], 0, 0, 0);
    }

    // epilogue
    const int zo = (MODE == 0 && swapz) ? 1 - z : z;
    float sc[4];
#pragma unroll
    for (int r = 0; r < 4; r++) {
        int m = m0 + wm * 64 + qo * 4 + r;   // i=0 base; per-i add 16 below (scale re-read cheap)
        sc[r] = 1.f;
        (void)m;
    }
#pragma unroll
    for (int i = 0; i < 4; i++) {
        int mb = m0 + wm * 64 + i * 16 + qo * 4;
        float scr[4];
#pragma unroll
        for (int r = 0; r < 4; r++)
            scr[r] = (MODE == 0 && scale && mb + r < N_PER) ? scale[z * N_PER + mb + r] : 1.f;
#pragma unroll
        for (int j = 0; j < 4; j++) {
            int col = n0 + wn * 64 + j * 16 + ml;
            float bv = bias[z * BCOLS + col];
#pragma unroll
            for (int r = 0; r < 4; r++) {
                int m = mb + r;
                if (m >= N_PER) continue;
                float vv = acc[i][j][r];
                if (MODE == 0) {
                    vv = vv * scr[r] + bv;
                    size_t idx = ((size_t)zo * N_PER + m) * 256 + col;
                    fout[idx] = base[idx] + vv;
                } else if (MODE == 1) {
                    vv += bv;
                    int mat = col >> 8, cc = col & 255;
                    bout[((size_t)mat * 2 * N_PER + (size_t)z * N_PER + m) * 256 + cc] = f2bf(vv);
                } else {
                    vv += bv;
                    vv = 0.5f * vv * (1.0f + erff(vv * 0.70710678118654752f));
                    bout[((size_t)z * N_PER + m) * 512 + col] = f2bf(vv);
                }
            }
        }
    }
}

extern "C" void kernel_launch(void* const* d_in, const int* in_sizes, int n_in,
                              void* d_out, int out_size, void* d_ws, size_t ws_size,
                              hipStream_t stream) {
    const float* h_in   = (const float*)d_in[0];
    const int*   e_src  = (const int*)d_in[1];
    const int*   e_dst  = (const int*)d_in[2];
    const float* pre_W  = (const float*)d_in[3];
    const float* pre_b  = (const float*)d_in[4];
    const float* post_W = (const float*)d_in[5];
    const float* post_b = (const float*)d_in[6];
    const float* q_W    = (const float*)d_in[7];
    const float* q_b    = (const float*)d_in[8];
    const float* k_W    = (const float*)d_in[9];
    const float* k_b    = (const float*)d_in[10];
    const float* v_W    = (const float*)d_in[11];
    const float* v_b    = (const float*)d_in[12];
    const float* o_W    = (const float*)d_in[13];
    const float* o_b    = (const float*)d_in[14];
    const float* ffn_W1 = (const float*)d_in[15];
    const float* ffn_b1 = (const float*)d_in[16];
    const float* ffn_W2 = (const float*)d_in[17];
    const float* ffn_b2 = (const float*)d_in[18];
    const float* ln_pre_g  = (const float*)d_in[19];
    const float* ln_pre_b  = (const float*)d_in[20];
    const float* ln_attn_g = (const float*)d_in[21];
    const float* ln_attn_b = (const float*)d_in[22];
    const float* ln_post_g = (const float*)d_in[23];
    const float* ln_post_b = (const float*)d_in[24];
    const float* ln_ffn_g  = (const float*)d_in[25];
    const float* ln_ffn_b  = (const float*)d_in[26];

    float* hout = (float*)d_out;
    char* ws = (char*)d_ws;

    const long AzH = (long)N_PER * HID;                 // 6.4M elems

    // workspace layout (bytes)
    ushort_t* hn    = (ushort_t*)(ws + 0);              // 25.6 MB bf16 [2][25000][256]
    ushort_t* qkv   = (ushort_t*)(ws + 25600000);       // 76.8 MB bf16 [3][2][25000][256]
    ushort_t* fb    = (ushort_t*)(ws + 25600000);       // 51.2 MB bf16 [2][25000][512] (aliases q+k)
    ushort_t* agg   = (ushort_t*)(ws + 102400000);      // 25.6 MB
    ushort_t* wT    = (ushort_t*)(ws + 128000000);      // 2.62 MB
    float* qkvbias  = (float*)(ws + 130621440);         // 6 KB
    float* cs       = (float*)(ws + 130627584);
    float* cd       = (float*)(ws + 130827584);
    int* cnt_s      = (int*)(ws + 131027584);
    int* cnt_d      = (int*)(ws + 131227584);
    int* off        = (int*)(ws + 131427584);
    int* cur        = (int*)(ws + 131627592);
    int* csr        = (int*)(ws + 131827592);

    const ushort_t* preWT  = wT;
    const ushort_t* postWT = wT + 131072;
    const ushort_t* qkvWT  = wT + 262144;
    const ushort_t* oWT    = wT + 655360;
    const ushort_t* w1T    = wT + 786432;
    const ushort_t* w2T    = wT + 1048576;
    ushort_t* qb = qkv;                                  // [2][N][256]
    ushort_t* kb = qkv + 2 * AzH;
    ushort_t* vb = qkv + 4 * AzH;

    hipMemsetAsync(cnt_s, 0, 400000, stream);            // cnt_s + cnt_d contiguous

    k_convw<<<5120, 256, 0, stream>>>(pre_W, post_W, q_W, k_W, v_W, o_W, ffn_W1, ffn_W2, wT);
    k_packbias<<<6, 256, 0, stream>>>(q_b, k_b, v_b, qkvbias);
    k_count<<<1563, 256, 0, stream>>>(e_src, e_dst, cnt_s, cnt_d);
    k_scale<<<196, 256, 0, stream>>>(cnt_s, cnt_d, cs, cd);
    k_scan<<<2, 1024, 0, stream>>>(cnt_d, off, cur);
    k_fill<<<1563, 256, 0, stream>>>(e_src, e_dst, cur, csr);

    // ---- stage 1: pre hetero-conv ----
    k_ln<<<12500, 256, 0, stream>>>(h_in, ln_pre_g, ln_pre_b, cs, hn);
    k_gather<<<12500, 256, 0, stream>>>(hn, off, csr, agg);
    k_gemm5<0, 8><<<dim3(196, 2, 2), 256, 0, stream>>>(agg, AzH, preWT, 65536, pre_b,
                                                       h_in, hout, 1, (ushort_t*)nullptr, cd);

    // ---- stage 2: sparse attention ----
    k_ln<<<12500, 256, 0, stream>>>(hout, ln_attn_g, ln_attn_b, (const float*)nullptr, hn);
    k_gemm5<1, 8><<<dim3(196, 6, 2), 256, 0, stream>>>(hn, AzH, qkvWT, 196608, qkvbias,
                                                       (const float*)nullptr, (float*)nullptr, 0,
                                                       qkv, (const float*)nullptr);
    k_attn<<<12500, 256, 0, stream>>>(qb, kb, vb, off, csr, agg);
    k_gemm5<0, 8><<<dim3(196, 2, 2), 256, 0, stream>>>(agg, AzH, oWT, 65536, o_b,
                                                       hout, hout, 0, (ushort_t*)nullptr,
                                                       (const float*)nullptr);

    // ---- stage 3: post hetero-conv ----
    k_ln<<<12500, 256, 0, stream>>>(hout, ln_post_g, ln_post_b, cs, hn);
    k_gather<<<12500, 256, 0, stream>>>(hn, off, csr, agg);
    k_gemm5<0, 8><<<dim3(196, 2, 2), 256, 0, stream>>>(agg, AzH, postWT, 65536, post_b,
                                                       hout, hout, 1, (ushort_t*)nullptr, cd);

    // ---- stage 4: FFN ----
    k_ln<<<12500, 256, 0, stream>>>(hout, ln_ffn_g, ln_ffn_b, (const float*)nullptr, hn);
    k_gemm5<2, 8><<<dim3(196, 4, 2), 256, 0, stream>>>(hn, AzH, w1T, 131072, ffn_b1,
                                                       (const float*)nullptr, (float*)nullptr, 0,
                                                       fb, (const float*)nullptr);
    k_gemm5<0, 16><<<dim3(196, 2, 2), 256, 0, stream>>>(fb, (long)N_PER * 512, w2T, 131072, ffn_b2,
                                                        hout, hout, 0, (ushort_t*)nullptr,
                                                        (const float*)nullptr);
}

// Round 6
// 654.758 us; speedup vs baseline: 1.6963x; 1.1604x over previous
//
#include <hip/hip_runtime.h>
#include <math.h>

#define N_PER 25000
#define HID 256
#define E_PER 200000

typedef unsigned short ushort_t;
typedef __attribute__((ext_vector_type(8))) unsigned short ushort8v;
typedef __attribute__((ext_vector_type(4))) unsigned short ushort4v;
typedef __attribute__((ext_vector_type(8))) __bf16 bf16x8;
typedef __attribute__((ext_vector_type(4))) float floatx4;

__device__ __forceinline__ float bf2f(unsigned short u) {
    union { unsigned int i; float f; } c; c.i = ((unsigned int)u) << 16; return c.f;
}
__device__ __forceinline__ unsigned short f2bf(float f) {
    union { float f; unsigned int i; } c; c.f = f;
    unsigned int i = c.i;
    return (unsigned short)((i + 0x7FFFu + ((i >> 16) & 1u)) >> 16);
}

// ---------------- degree counting ----------------
__global__ void k_count(const int* __restrict__ es, const int* __restrict__ ed,
                        int* __restrict__ cnt_s, int* __restrict__ cnt_d) {
    int i = blockIdx.x * 256 + threadIdx.x;
    if (i >= 2 * E_PER) return;
    int et = i / E_PER;
    atomicAdd(&cnt_s[et * N_PER + es[i]], 1);
    atomicAdd(&cnt_d[et * N_PER + ed[i]], 1);
}

__global__ void k_scale(const int* __restrict__ cnt_s, const int* __restrict__ cnt_d,
                        float* __restrict__ cs, float* __restrict__ cd) {
    int i = blockIdx.x * 256 + threadIdx.x;
    if (i >= 2 * N_PER) return;
    cs[i] = rsqrtf(fmaxf((float)cnt_s[i], 1.f));
    cd[i] = rsqrtf(fmaxf((float)cnt_d[i], 1.f));
}

// ---------------- CSR build: scan + fill ----------------
__global__ __launch_bounds__(1024) void k_scan(const int* __restrict__ cnt,
                                               int* __restrict__ off, int* __restrict__ cur) {
    int et = blockIdx.x, t = threadIdx.x;
    const int* c = cnt + et * N_PER;
    int loc[25]; int tot = 0;
#pragma unroll
    for (int j = 0; j < 25; j++) {
        int idx = t * 25 + j;
        int v = (idx < N_PER) ? c[idx] : 0;
        loc[j] = tot; tot += v;
    }
    __shared__ int sb[1024];
    sb[t] = tot; __syncthreads();
    for (int d = 1; d < 1024; d <<= 1) {
        int v = (t >= d) ? sb[t - d] : 0;
        __syncthreads();
        sb[t] += v;
        __syncthreads();
    }
    int base = sb[t] - tot;
#pragma unroll
    for (int j = 0; j < 25; j++) {
        int idx = t * 25 + j;
        if (idx <= N_PER) {
            int val = base + loc[j];
            off[et * (N_PER + 1) + idx] = val;
            if (idx < N_PER) cur[et * N_PER + idx] = val;
        }
    }
}

__global__ void k_fill(const int* __restrict__ es, const int* __restrict__ ed,
                       int* __restrict__ cur, int* __restrict__ csr) {
    int i = blockIdx.x * 256 + threadIdx.x;
    if (i >= 2 * E_PER) return;
    int et = i / E_PER;
    int d = ed[i];
    int pos = atomicAdd(&cur[et * N_PER + d], 1);
    csr[et * E_PER + pos] = es[i];
}

// ---------------- weight convert ----------------
// new layout (elems):
//   qkv  [2][768][256]   (col-major [col][K])        @ 0
//   w1   [2][512][256]   (col-major)                 @ 393216
//   pre  [2][8][256][32] (k-chunk packed)            @ 655360
//   post [2][8][256][32]                             @ 786432
//   o    [2][8][256][32]                             @ 917504
//   w2   [2][16][256][32]                            @ 1048576
__global__ void k_convw(const float* __restrict__ pre, const float* __restrict__ post,
                        const float* __restrict__ qW, const float* __restrict__ kW,
                        const float* __restrict__ vW, const float* __restrict__ oW,
                        const float* __restrict__ w1, const float* __restrict__ w2,
                        ushort_t* __restrict__ out) {
    int i = blockIdx.x * 256 + threadIdx.x;
    if (i >= 1310720) return;
    float v;
    if (i < 393216) {                        // qkv col-major
        int z = (i >= 196608) ? 1 : 0;
        int r = i - z * 196608;
        int row = r >> 8, k = r & 255;
        int mat = row >> 8, c = row & 255;
        const float* src = (mat == 0) ? qW : (mat == 1) ? kW : vW;
        v = src[z * 65536 + k * 256 + c];
    } else if (i < 655360) {                 // w1 col-major
        int j = i - 393216; int z = j >> 17, r = j & 131071;
        int n = r >> 8, k = r & 255;
        v = w1[z * 131072 + k * 512 + n];
    } else if (i < 1048576) {                // pre/post/o packed
        int j = i - 655360; int mat = j >> 17;
        int e = j & 131071; int z = e >> 16; int q2 = e & 65535;
        int kc = q2 >> 13, col = (q2 >> 5) & 255, k32 = q2 & 31;
        const float* src = (mat == 0) ? pre : (mat == 1) ? post : oW;
        v = src[z * 65536 + (kc * 32 + k32) * 256 + col];
    } else {                                 // w2 packed
        int j = i - 1048576; int z = j >> 17; int e = j & 131071;
        int kc = e >> 13, col = (e >> 5) & 255, k32 = e & 31;
        v = w2[z * 131072 + (kc * 32 + k32) * 256 + col];
    }
    out[i] = f2bf(v);
}

// pack q/k/v biases -> [2][768]
__global__ void k_packbias(const float* __restrict__ qb, const float* __restrict__ kb,
                           const float* __restrict__ vb, float* __restrict__ out) {
    int i = blockIdx.x * 256 + threadIdx.x;
    if (i >= 1536) return;
    int z = i / 768, c = i % 768;
    int mat = c >> 8, cc = c & 255;
    const float* src = (mat == 0) ? qb : (mat == 1) ? kb : vb;
    out[i] = src[z * 256 + cc];
}

// ---------------- LayerNorm (+optional cs scale) -> bf16 ----------------
__global__ __launch_bounds__(256) void k_ln(const float* __restrict__ h,
                                            const float* __restrict__ g, const float* __restrict__ b,
                                            const float* __restrict__ cs, ushort_t* __restrict__ out) {
    int lane = threadIdx.x & 63;
    int row = blockIdx.x * 4 + (threadIdx.x >> 6);
    int ty = row >= N_PER;
    float4 x = *(const float4*)(h + (size_t)row * HID + lane * 4);
    float s = x.x + x.y + x.z + x.w;
    float q = x.x * x.x + x.y * x.y + x.z * x.z + x.w * x.w;
    for (int m = 1; m < 64; m <<= 1) {
        s += __shfl_xor(s, m, 64);
        q += __shfl_xor(q, m, 64);
    }
    float mean = s * (1.f / 256.f);
    float var = q * (1.f / 256.f) - mean * mean;
    float rs = rsqrtf(var + 1e-5f);
    float sc = cs ? cs[row] : 1.f;
    int c = lane * 4;
    const float* gp = g + ty * HID + c;
    const float* bp = b + ty * HID + c;
    float xv[4] = {x.x, x.y, x.z, x.w};
    ushort4v o;
#pragma unroll
    for (int i = 0; i < 4; i++) {
        float y = ((xv[i] - mean) * rs * gp[i] + bp[i]) * sc;
        o[i] = f2bf(y);
    }
    *(ushort4v*)(out + (size_t)row * HID + c) = o;
}

// ---------------- conv gather (4-wide unrolled) ----------------
__global__ __launch_bounds__(256) void k_gather(const ushort_t* __restrict__ hn,
                                                const int* __restrict__ off, const int* __restrict__ csr,
                                                ushort_t* __restrict__ agg) {
    int lane = threadIdx.x & 63;
    int row = blockIdx.x * 4 + (threadIdx.x >> 6);
    int dt = row >= N_PER;
    int n = row - dt * N_PER;
    int et = 1 - dt;
    int s0 = off[et * (N_PER + 1) + n], s1 = off[et * (N_PER + 1) + n + 1];
    const ushort_t* hb = hn + (size_t)et * N_PER * HID + lane * 4;
    const int* list = csr + et * E_PER;
    float a0 = 0, a1 = 0, a2 = 0, a3 = 0;
    int e = s0;
    for (; e + 4 <= s1; e += 4) {
        int ia = list[e], ib = list[e + 1], ic = list[e + 2], id = list[e + 3];
        ushort4v ua = *(const ushort4v*)(hb + (size_t)ia * HID);
        ushort4v ub = *(const ushort4v*)(hb + (size_t)ib * HID);
        ushort4v uc = *(const ushort4v*)(hb + (size_t)ic * HID);
        ushort4v ud = *(const ushort4v*)(hb + (size_t)id * HID);
        a0 += bf2f(ua[0]) + bf2f(ub[0]) + bf2f(uc[0]) + bf2f(ud[0]);
        a1 += bf2f(ua[1]) + bf2f(ub[1]) + bf2f(uc[1]) + bf2f(ud[1]);
        a2 += bf2f(ua[2]) + bf2f(ub[2]) + bf2f(uc[2]) + bf2f(ud[2]);
        a3 += bf2f(ua[3]) + bf2f(ub[3]) + bf2f(uc[3]) + bf2f(ud[3]);
    }
    for (; e < s1; ++e) {
        int src = list[e];
        ushort4v u = *(const ushort4v*)(hb + (size_t)src * HID);
        a0 += bf2f(u[0]); a1 += bf2f(u[1]); a2 += bf2f(u[2]); a3 += bf2f(u[3]);
    }
    ushort4v o; o[0] = f2bf(a0); o[1] = f2bf(a1); o[2] = f2bf(a2); o[3] = f2bf(a3);
    *(ushort4v*)(agg + ((size_t)et * N_PER + n) * HID + lane * 4) = o;
}

// ---------------- fused edge softmax attention (2-wide unrolled) ----------------
__global__ __launch_bounds__(256) void k_attn(const ushort_t* __restrict__ q,
                                              const ushort_t* __restrict__ k, const ushort_t* __restrict__ v,
                                              const int* __restrict__ off, const int* __restrict__ csr,
                                              ushort_t* __restrict__ outb) {
    int lane = threadIdx.x & 63;
    int row = blockIdx.x * 4 + (threadIdx.x >> 6);
    int dt = row >= N_PER;
    int n = row - dt * N_PER;
    int et = 1 - dt;
    int s0 = off[et * (N_PER + 1) + n], s1 = off[et * (N_PER + 1) + n + 1];
    ushort4v qu = *(const ushort4v*)(q + (size_t)row * HID + lane * 4);
    float q0 = bf2f(qu[0]), q1 = bf2f(qu[1]), q2 = bf2f(qu[2]), q3 = bf2f(qu[3]);
    const ushort_t* kb = k + (size_t)et * N_PER * HID + lane * 4;
    const ushort_t* vb = v + (size_t)et * N_PER * HID + lane * 4;
    const int* list = csr + et * E_PER;
    float l = 0.f;
    float O0 = 0, O1 = 0, O2 = 0, O3 = 0;
    int e = s0;
    for (; e + 2 <= s1; e += 2) {
        int ia = list[e], ib = list[e + 1];
        ushort4v kua = *(const ushort4v*)(kb + (size_t)ia * HID);
        ushort4v vua = *(const ushort4v*)(vb + (size_t)ia * HID);
        ushort4v kub = *(const ushort4v*)(kb + (size_t)ib * HID);
        ushort4v vub = *(const ushort4v*)(vb + (size_t)ib * HID);
        float da = q0 * bf2f(kua[0]) + q1 * bf2f(kua[1]) + q2 * bf2f(kua[2]) + q3 * bf2f(kua[3]);
        float db = q0 * bf2f(kub[0]) + q1 * bf2f(kub[1]) + q2 * bf2f(kub[2]) + q3 * bf2f(kub[3]);
        da += __shfl_xor(da, 1, 64); db += __shfl_xor(db, 1, 64);
        da += __shfl_xor(da, 2, 64); db += __shfl_xor(db, 2, 64);
        da += __shfl_xor(da, 4, 64); db += __shfl_xor(db, 4, 64);
        float sa = fminf(5.f, fmaxf(-5.f, da * 0.17677669529663687f));
        float sb = fminf(5.f, fmaxf(-5.f, db * 0.17677669529663687f));
        float pa = __expf(sa), pb = __expf(sb);
        l += pa + pb;
        O0 += pa * bf2f(vua[0]) + pb * bf2f(vub[0]);
        O1 += pa * bf2f(vua[1]) + pb * bf2f(vub[1]);
        O2 += pa * bf2f(vua[2]) + pb * bf2f(vub[2]);
        O3 += pa * bf2f(vua[3]) + pb * bf2f(vub[3]);
    }
    if (e < s1) {
        int src = list[e];
        ushort4v ku = *(const ushort4v*)(kb + (size_t)src * HID);
        ushort4v vu = *(const ushort4v*)(vb + (size_t)src * HID);
        float d = q0 * bf2f(ku[0]) + q1 * bf2f(ku[1]) + q2 * bf2f(ku[2]) + q3 * bf2f(ku[3]);
        d += __shfl_xor(d, 1, 64);
        d += __shfl_xor(d, 2, 64);
        d += __shfl_xor(d, 4, 64);
        float s = fminf(5.f, fmaxf(-5.f, d * 0.17677669529663687f));
        float p = __expf(s);
        l += p;
        O0 += p * bf2f(vu[0]); O1 += p * bf2f(vu[1]);
        O2 += p * bf2f(vu[2]); O3 += p * bf2f(vu[3]);
    }
    float inv = (l > 0.f) ? 1.f / l : 0.f;
    ushort4v o;
    o[0] = f2bf(O0 * inv); o[1] = f2bf(O1 * inv); o[2] = f2bf(O2 * inv); o[3] = f2bf(O3 * inv);
    *(ushort4v*)(outb + (size_t)row * HID + lane * 4) = o;
}

// ---------------- full-row conv GEMM + residual + fused LayerNorm ----------------
// Block: 128 rows x 256 cols, 512 threads = 8 waves, wave w owns rows w*16..w*16+15.
// B packed [K/32][256][32]: per k-iter the 16KB B-chunk is contiguous -> fully
// coalesced stage into Bs[col][32]. A loaded global->register (read exactly once).
// Epilogue: h_new = base + acc*convscale + bias (fp32 write), then row-LN via
// shfl_xor over the 16 ml-lanes, emitting hn = LN(h_new)*lncs in bf16.
template <int KT, bool LN>
__global__ __launch_bounds__(512, 2)
void k_cgemm(const ushort_t* __restrict__ A, long Az,
             const ushort_t* __restrict__ Bpk, long Bz,
             const float* __restrict__ bias,
             const float* __restrict__ base, float* __restrict__ fout, int swapz,
             const float* __restrict__ convscale,
             const float* __restrict__ g, const float* __restrict__ b,
             const float* __restrict__ lncs, ushort_t* __restrict__ hnout) {
    constexpr int K = KT * 32;
    __shared__ __align__(16) ushort_t Bs[256 * 32];    // 16 KB, [col][32]
    const int t = threadIdx.x;
    const int lane = t & 63, w = t >> 6;
    const int ml = lane & 15, qo = lane >> 4;
    const int z = blockIdx.z;
    const int m0 = blockIdx.x * 128;
    const ushort_t* Ab = A + (long)z * Az;
    const ushort_t* Bp = Bpk + (long)z * Bz;
    const ushort8v z8 = {0, 0, 0, 0, 0, 0, 0, 0};

    const int arow = m0 + w * 16 + ml;
    const bool aok = arow < N_PER;
    const long abase = (long)arow * K + qo * 8;

    floatx4 acc[16];
#pragma unroll
    for (int j = 0; j < 16; j++) acc[j] = (floatx4){0.f, 0.f, 0.f, 0.f};

    for (int kt = 0; kt < KT; kt++) {
        if (kt) __syncthreads();
        const ushort_t* gs = Bp + (long)kt * 8192;
        ushort8v c0 = *(const ushort8v*)(gs + t * 8);
        ushort8v c1 = *(const ushort8v*)(gs + 4096 + t * 8);
        ushort8v af = aok ? *(const ushort8v*)(Ab + abase + kt * 32) : z8;
        *(ushort8v*)(Bs + t * 8) = c0;
        *(ushort8v*)(Bs + 4096 + t * 8) = c1;
        __syncthreads();
#pragma unroll
        for (int j = 0; j < 16; j++) {
            bf16x8 bfr = *(const bf16x8*)(Bs + (j * 16 + ml) * 32 + qo * 8);
            acc[j] = __builtin_amdgcn_mfma_f32_16x16x32_bf16(*(bf16x8*)&af, bfr, acc[j], 0, 0, 0);
        }
    }

    const int zo = swapz ? 1 - z : z;
    const int mb = m0 + w * 16 + qo * 4;
    float cs4[4];
#pragma unroll
    for (int r = 0; r < 4; r++)
        cs4[r] = (convscale && mb + r < N_PER) ? convscale[z * N_PER + mb + r] : 1.f;
    float biasv[16], gv[16], bv[16];
#pragma unroll
    for (int j = 0; j < 16; j++) {
        int col = j * 16 + ml;
        biasv[j] = bias[z * 256 + col];
        if (LN) { gv[j] = g[zo * 256 + col]; bv[j] = b[zo * 256 + col]; }
    }

    float s1[4] = {0, 0, 0, 0}, s2[4] = {0, 0, 0, 0};
#pragma unroll
    for (int r = 0; r < 4; r++) {
        int m = mb + r;
        if (m >= N_PER) continue;
        size_t rowb = ((size_t)zo * N_PER + m) * 256 + ml;
#pragma unroll
        for (int j = 0; j < 16; j++) {
            float vv = acc[j][r] * cs4[r] + biasv[j];
            float hv = base[rowb + j * 16] + vv;
            fout[rowb + j * 16] = hv;
            acc[j][r] = hv;
            if (LN) { s1[r] += hv; s2[r] += hv * hv; }
        }
    }
    if (LN) {
#pragma unroll
        for (int r = 0; r < 4; r++) {
#pragma unroll
            for (int mm = 1; mm < 16; mm <<= 1) {
                s1[r] += __shfl_xor(s1[r], mm, 64);
                s2[r] += __shfl_xor(s2[r], mm, 64);
            }
        }
#pragma unroll
        for (int r = 0; r < 4; r++) {
            int m = mb + r;
            if (m >= N_PER) continue;
            float mean = s1[r] * (1.f / 256.f);
            float var = s2[r] * (1.f / 256.f) - mean * mean;
            float rs = rsqrtf(var + 1e-5f);
            float sc = lncs ? lncs[zo * N_PER + m] : 1.f;
            size_t rowb = ((size_t)zo * N_PER + m) * 256 + ml;
#pragma unroll
            for (int j = 0; j < 16; j++) {
                float y = ((acc[j][r] - mean) * rs * gv[j] + bv[j]) * sc;
                hnout[rowb + j * 16] = f2bf(y);
            }
        }
    }
}

// ---------------- m97-style 128x128 dbuf GEMM (qkv / ffn1, bf16 out) ----------------
// MODE 1: qkv bf16 split by col>>8;  MODE 2: ffn1 bf16 gelu, row stride 512
template <int MODE, int KT>
__global__ __launch_bounds__(256, 3)
void k_gemm5(const ushort_t* __restrict__ A, long Az,
             const ushort_t* __restrict__ BT, long Bz,
             const float* __restrict__ bias,
             ushort_t* __restrict__ bout) {
    constexpr int K = KT * 32;
    constexpr int BCOLS = (MODE == 1) ? 768 : 512;
    __shared__ __align__(16) ushort_t As[2][128 * 32];
    __shared__ __align__(16) ushort_t Bs[2][128 * 32];
    const int t = threadIdx.x;
    const int lane = t & 63, w = t >> 6;
    const int wm = w & 1, wn = w >> 1;
    const int ml = lane & 15, qo = lane >> 4;
    const int z = blockIdx.z;
    const int m0 = blockIdx.x * 128, n0 = blockIdx.y * 128;
    const ushort_t* Ab = A + (long)z * Az;
    const ushort_t* Bb = BT + (long)z * Bz;
    const ushort8v z8 = {0, 0, 0, 0, 0, 0, 0, 0};

    const int srow = t >> 1;
    const int sc0 = (t & 1) * 2;
    const int garow = m0 + srow;
    const long aGb = (long)garow * K + sc0 * 8;
    const long bGb = (long)(n0 + srow) * K + sc0 * 8;
    const int sw0 = srow * 32 + ((sc0 ^ (srow & 3)) << 3);
    const int sw1 = srow * 32 + (((sc0 + 1) ^ (srow & 3)) << 3);
    const bool aok = garow < N_PER;

    int aro[4], bro[4];
#pragma unroll
    for (int i = 0; i < 4; i++) {
        aro[i] = (wm * 64 + i * 16 + ml) * 32 + ((qo ^ (ml & 3)) << 3);
        bro[i] = (wn * 64 + i * 16 + ml) * 32 + ((qo ^ (ml & 3)) << 3);
    }

    floatx4 acc[4][4];
#pragma unroll
    for (int i = 0; i < 4; i++)
#pragma unroll
        for (int j = 0; j < 4; j++) acc[i][j] = (floatx4){0.f, 0.f, 0.f, 0.f};

    {
        ushort8v a0 = aok ? *(const ushort8v*)(Ab + aGb) : z8;
        ushort8v a1 = aok ? *(const ushort8v*)(Ab + aGb + 8) : z8;
        ushort8v b0 = *(const ushort8v*)(Bb + bGb);
        ushort8v b1 = *(const ushort8v*)(Bb + bGb + 8);
        *(ushort8v*)(As[0] + sw0) = a0;
        *(ushort8v*)(As[0] + sw1) = a1;
        *(ushort8v*)(Bs[0] + sw0) = b0;
        *(ushort8v*)(Bs[0] + sw1) = b1;
    }

#pragma unroll
    for (int kt = 0; kt < KT; kt++) {
        __syncthreads();
        const int cur = kt & 1;
        bf16x8 af[4], bf[4];
#pragma unroll
        for (int i = 0; i < 4; i++) {
            af[i] = *(const bf16x8*)(As[cur] + aro[i]);
            bf[i] = *(const bf16x8*)(Bs[cur] + bro[i]);
        }
        if (kt + 1 < KT) {
            const int nk = (kt + 1) * 32;
            ushort8v a0 = aok ? *(const ushort8v*)(Ab + aGb + nk) : z8;
            ushort8v a1 = aok ? *(const ushort8v*)(Ab + aGb + nk + 8) : z8;
            ushort8v b0 = *(const ushort8v*)(Bb + bGb + nk);
            ushort8v b1 = *(const ushort8v*)(Bb + bGb + nk + 8);
            const int nb = cur ^ 1;
            *(ushort8v*)(As[nb] + sw0) = a0;
            *(ushort8v*)(As[nb] + sw1) = a1;
            *(ushort8v*)(Bs[nb] + sw0) = b0;
            *(ushort8v*)(Bs[nb] + sw1) = b1;
        }
#pragma unroll
        for (int i = 0; i < 4; i++)
#pragma unroll
            for (int j = 0; j < 4; j++)
                acc[i][j] = __builtin_amdgcn_mfma_f32_16x16x32_bf16(af[i], bf[j], acc[i][j], 0, 0, 0);
    }

#pragma unroll
    for (int i = 0; i < 4; i++) {
        int mb = m0 + wm * 64 + i * 16 + qo * 4;
#pragma unroll
        for (int j = 0; j < 4; j++) {
            int col = n0 + wn * 64 + j * 16 + ml;
            float bv = bias[z * BCOLS + col];
#pragma unroll
            for (int r = 0; r < 4; r++) {
                int m = mb + r;
                if (m >= N_PER) continue;
                float vv = acc[i][j][r] + bv;
                if (MODE == 2) {
                    vv = 0.5f * vv * (1.0f + erff(vv * 0.70710678118654752f));
                    bout[((size_t)z * N_PER + m) * 512 + col] = f2bf(vv);
                } else {
                    int mat = col >> 8, cc = col & 255;
                    bout[((size_t)mat * 2 * N_PER + (size_t)z * N_PER + m) * 256 + cc] = f2bf(vv);
                }
            }
        }
    }
}

extern "C" void kernel_launch(void* const* d_in, const int* in_sizes, int n_in,
                              void* d_out, int out_size, void* d_ws, size_t ws_size,
                              hipStream_t stream) {
    const float* h_in   = (const float*)d_in[0];
    const int*   e_src  = (const int*)d_in[1];
    const int*   e_dst  = (const int*)d_in[2];
    const float* pre_W  = (const float*)d_in[3];
    const float* pre_b  = (const float*)d_in[4];
    const float* post_W = (const float*)d_in[5];
    const float* post_b = (const float*)d_in[6];
    const float* q_W    = (const float*)d_in[7];
    const float* q_b    = (const float*)d_in[8];
    const float* k_W    = (const float*)d_in[9];
    const float* k_b    = (const float*)d_in[10];
    const float* v_W    = (const float*)d_in[11];
    const float* v_b    = (const float*)d_in[12];
    const float* o_W    = (const float*)d_in[13];
    const float* o_b    = (const float*)d_in[14];
    const float* ffn_W1 = (const float*)d_in[15];
    const float* ffn_b1 = (const float*)d_in[16];
    const float* ffn_W2 = (const float*)d_in[17];
    const float* ffn_b2 = (const float*)d_in[18];
    const float* ln_pre_g  = (const float*)d_in[19];
    const float* ln_pre_b  = (const float*)d_in[20];
    const float* ln_attn_g = (const float*)d_in[21];
    const float* ln_attn_b = (const float*)d_in[22];
    const float* ln_post_g = (const float*)d_in[23];
    const float* ln_post_b = (const float*)d_in[24];
    const float* ln_ffn_g  = (const float*)d_in[25];
    const float* ln_ffn_b  = (const float*)d_in[26];

    float* hout = (float*)d_out;
    char* ws = (char*)d_ws;

    const long AzH = (long)N_PER * HID;

    // workspace layout (bytes)
    ushort_t* hn    = (ushort_t*)(ws + 0);              // 25.6 MB bf16 [2][25000][256]
    ushort_t* qkv   = (ushort_t*)(ws + 25600000);       // 76.8 MB bf16 [3][2][25000][256]
    ushort_t* fb    = (ushort_t*)(ws + 25600000);       // 51.2 MB bf16 [2][25000][512] (aliases q+k)
    ushort_t* agg   = (ushort_t*)(ws + 102400000);      // 25.6 MB
    ushort_t* wT    = (ushort_t*)(ws + 128000000);      // 2.62 MB
    float* qkvbias  = (float*)(ws + 130621440);
    float* cs       = (float*)(ws + 130627584);
    float* cd       = (float*)(ws + 130827584);
    int* cnt_s      = (int*)(ws + 131027584);
    int* cnt_d      = (int*)(ws + 131227584);
    int* off        = (int*)(ws + 131427584);
    int* cur        = (int*)(ws + 131627592);
    int* csr        = (int*)(ws + 131827592);

    const ushort_t* qkvWT = wT;
    const ushort_t* w1T   = wT + 393216;
    const ushort_t* preP  = wT + 655360;
    const ushort_t* postP = wT + 786432;
    const ushort_t* oP    = wT + 917504;
    const ushort_t* w2P   = wT + 1048576;
    ushort_t* qb = qkv;
    ushort_t* kb = qkv + 2 * AzH;
    ushort_t* vb = qkv + 4 * AzH;

    hipMemsetAsync(cnt_s, 0, 400000, stream);

    k_convw<<<5120, 256, 0, stream>>>(pre_W, post_W, q_W, k_W, v_W, o_W, ffn_W1, ffn_W2, wT);
    k_packbias<<<6, 256, 0, stream>>>(q_b, k_b, v_b, qkvbias);
    k_count<<<1563, 256, 0, stream>>>(e_src, e_dst, cnt_s, cnt_d);
    k_scale<<<196, 256, 0, stream>>>(cnt_s, cnt_d, cs, cd);
    k_scan<<<2, 1024, 0, stream>>>(cnt_d, off, cur);
    k_fill<<<1563, 256, 0, stream>>>(e_src, e_dst, cur, csr);

    // ---- stage 1: pre hetero-conv (+fused LN_attn) ----
    k_ln<<<12500, 256, 0, stream>>>(h_in, ln_pre_g, ln_pre_b, cs, hn);
    k_gather<<<12500, 256, 0, stream>>>(hn, off, csr, agg);
    k_cgemm<8, true><<<dim3(196, 1, 2), 512, 0, stream>>>(
        agg, AzH, preP, 65536, pre_b, h_in, hout, 1, cd,
        ln_attn_g, ln_attn_b, (const float*)nullptr, hn);

    // ---- stage 2: sparse attention (+fused LN_post w/ cs) ----
    k_gemm5<1, 8><<<dim3(196, 6, 2), 256, 0, stream>>>(hn, AzH, qkvWT, 196608, qkvbias, qkv);
    k_attn<<<12500, 256, 0, stream>>>(qb, kb, vb, off, csr, agg);
    k_cgemm<8, true><<<dim3(196, 1, 2), 512, 0, stream>>>(
        agg, AzH, oP, 65536, o_b, hout, hout, 0, (const float*)nullptr,
        ln_post_g, ln_post_b, cs, hn);

    // ---- stage 3: post hetero-conv (+fused LN_ffn) ----
    k_gather<<<12500, 256, 0, stream>>>(hn, off, csr, agg);
    k_cgemm<8, true><<<dim3(196, 1, 2), 512, 0, stream>>>(
        agg, AzH, postP, 65536, post_b, hout, hout, 1, cd,
        ln_ffn_g, ln_ffn_b, (const float*)nullptr, hn);

    // ---- stage 4: FFN ----
    k_gemm5<2, 8><<<dim3(196, 4, 2), 256, 0, stream>>>(hn, AzH, w1T, 131072, ffn_b1, fb);
    k_cgemm<16, false><<<dim3(196, 1, 2), 512, 0, stream>>>(
        fb, (long)N_PER * 512, w2P, 131072, ffn_b2, hout, hout, 0, (const float*)nullptr,
        (const float*)nullptr, (const float*)nullptr, (const float*)nullptr, (ushort_t*)nullptr);
}